// Round 10
// baseline (552.746 us; speedup 1.0000x reference)
//
#include <hip/hip_runtime.h>
#include <hip/hip_bf16.h>

#define N_NODES 100000
#define N_EDGES 3200000
#define IN_F 128
#define OUT_F 64
#define HEADS 8
#define ALPHA 0.2f

#define BSHIFT 7
#define NBUCK 782           // ceil(100000 / 128)
#define CHUNK 16384         // edges per partition block
#define NPBLK 196           // ceil(N_EDGES / CHUNK)

typedef __bf16 bf16x8 __attribute__((ext_vector_type(8)));
typedef float f32x4 __attribute__((ext_vector_type(4)));
typedef __attribute__((ext_vector_type(8))) unsigned short ushort8;

static __device__ __forceinline__ unsigned short f2b(float f) {
    __hip_bfloat16 h = __float2bfloat16(f);
    return __builtin_bit_cast(unsigned short, h);
}
static __device__ __forceinline__ float b2f(unsigned short u) {
    unsigned int x = ((unsigned int)u) << 16;
    return __builtin_bit_cast(float, x);
}

static __device__ __forceinline__ void gll16(const void* g, void* l) {
    __builtin_amdgcn_global_load_lds(
        (const __attribute__((address_space(1))) void*)g,
        (__attribute__((address_space(3))) void*)l, 16, 0, 0);
}

// ---------------- W transpose+convert: Wt[c=h*64+f][k] bf16 ----------------
__global__ void k_prep_w(const float* __restrict__ W, unsigned short* __restrict__ Wt) {
    int idx = blockIdx.x * 256 + threadIdx.x;
    if (idx >= HEADS * OUT_F * IN_F) return;
    int k = idx & 127;
    int c = idx >> 7;
    int h = c >> 6;
    int f = c & 63;
    Wt[idx] = f2b(W[h * IN_F * OUT_F + k * OUT_F + f]);
}

// ---------------- u[h][k] = sum_f W[h][k][f]*a[h][f]; v with a[h][64+f] ----
__global__ __launch_bounds__(1024) void k_uv(const float* __restrict__ W,
                                             const float* __restrict__ a,
                                             float* __restrict__ u, float* __restrict__ v) {
    int t = threadIdx.x;
    int h = t >> 7, k = t & 127;
    const float* Wrow = W + h * IN_F * OUT_F + k * OUT_F;
    const float* ah = a + h * 2 * OUT_F;
    float su = 0.f, sv = 0.f;
    for (int f = 0; f < OUT_F; ++f) {
        float wv = Wrow[f];
        su += wv * ah[f];
        sv += wv * ah[OUT_F + f];
    }
    u[t] = su;
    v[t] = sv;
}

// ------- fused: x -> bf16 copy, and logits asrc/atgt via u,v dots ----------
__global__ __launch_bounds__(256) void k_xadot(const float* __restrict__ x,
                                               const float* __restrict__ u,
                                               const float* __restrict__ v,
                                               unsigned short* __restrict__ xb,
                                               float* __restrict__ asrc,
                                               float* __restrict__ atgt) {
    int node = (blockIdx.x * 256 + threadIdx.x) >> 6;
    int lane = threadIdx.x & 63;
    if (node >= N_NODES) return;
    float2 xv = *reinterpret_cast<const float2*>(x + (size_t)node * 128 + 2 * lane);
    ushort2 pv = make_ushort2(f2b(xv.x), f2b(xv.y));
    *reinterpret_cast<ushort2*>(xb + (size_t)node * 128 + 2 * lane) = pv;
    for (int h = 0; h < 8; ++h) {
        float2 uu = *reinterpret_cast<const float2*>(u + h * 128 + 2 * lane);
        float2 vv = *reinterpret_cast<const float2*>(v + h * 128 + 2 * lane);
        float s1 = xv.x * uu.x + xv.y * uu.y;
        float s2 = xv.x * vv.x + xv.y * vv.y;
        for (int d = 1; d < 64; d <<= 1) {
            s1 += __shfl_xor(s1, d);
            s2 += __shfl_xor(s2, d);
        }
        if (lane == 0) {
            asrc[node * 8 + h] = s1;
            atgt[node * 8 + h] = s2;
        }
    }
}

// ---------------- pass 0: global bucket histogram (LDS-privatized) --------
__global__ __launch_bounds__(256) void k_bcount(const int* __restrict__ src,
                                                int* __restrict__ bhist) {
    __shared__ int h[NBUCK];
    for (int i = threadIdx.x; i < NBUCK; i += 256) h[i] = 0;
    __syncthreads();
    int i0 = blockIdx.x * CHUNK;
    int iend = i0 + CHUNK;
    if (iend > N_EDGES) iend = N_EDGES;
    for (int i = i0 + threadIdx.x; i < iend; i += 256)
        atomicAdd(&h[src[i] >> BSHIFT], 1);
    __syncthreads();
    for (int i = threadIdx.x; i < NBUCK; i += 256)
        if (h[i]) atomicAdd(&bhist[i], h[i]);
}

// ---------------- bucket scan (1 block); also init cursors ----------------
__global__ __launch_bounds__(1024) void k_bscan(const int* __restrict__ bhist,
                                                int* __restrict__ bstart,
                                                int* __restrict__ bcursor,
                                                int* __restrict__ rowptr) {
    __shared__ int s[1024];
    int t = threadIdx.x;
    int v = (t < NBUCK) ? bhist[t] : 0;
    s[t] = v;
    __syncthreads();
    for (int d = 1; d < 1024; d <<= 1) {
        int add = (t >= d) ? s[t - d] : 0;
        __syncthreads();
        s[t] += add;
        __syncthreads();
    }
    if (t < NBUCK) {
        int st = s[t] - v;
        bstart[t] = st;
        bcursor[t] = st;
    }
    if (t == 0) {
        bstart[NBUCK] = N_EDGES;
        rowptr[N_NODES] = N_EDGES;
    }
}

// ---------------- pass 1: partition edges into bucket regions -------------
__global__ __launch_bounds__(256) void k_bscatter(const int* __restrict__ src,
                                                  const int* __restrict__ tgt,
                                                  int* __restrict__ bcursor,
                                                  uint2* __restrict__ pairs) {
    __shared__ int h[NBUCK];
    __shared__ int rsv[NBUCK];
    for (int i = threadIdx.x; i < NBUCK; i += 256) h[i] = 0;
    __syncthreads();
    int i0 = blockIdx.x * CHUNK;
    int iend = i0 + CHUNK;
    if (iend > N_EDGES) iend = N_EDGES;
    for (int i = i0 + threadIdx.x; i < iend; i += 256)
        atomicAdd(&h[src[i] >> BSHIFT], 1);
    __syncthreads();
    for (int i = threadIdx.x; i < NBUCK; i += 256) {
        int c = h[i];
        rsv[i] = c ? atomicAdd(&bcursor[i], c) : 0;
        h[i] = 0;
    }
    __syncthreads();
    for (int i = i0 + threadIdx.x; i < iend; i += 256) {
        int s = src[i];
        int b = s >> BSHIFT;
        int p = rsv[b] + atomicAdd(&h[b], 1);
        pairs[p] = make_uint2((unsigned)s, (unsigned)tgt[i]);
    }
}

// ---------------- pass 2: in-bucket counting sort -> stgt + rowptr --------
__global__ __launch_bounds__(256) void k_bsort(const uint2* __restrict__ pairs,
                                               const int* __restrict__ bstart,
                                               int* __restrict__ rowptr,
                                               int* __restrict__ stgt) {
    __shared__ int h[128];
    __shared__ int s[128];
    int b = blockIdx.x;
    int p0 = bstart[b], p1 = bstart[b + 1];
    int n0 = b << BSHIFT;
    int t = threadIdx.x;
    if (t < 128) h[t] = 0;
    __syncthreads();
    for (int i = p0 + t; i < p1; i += 256)
        atomicAdd(&h[pairs[i].x & 127], 1);
    __syncthreads();
    int v = (t < 128) ? h[t] : 0;
    if (t < 128) s[t] = v;
    __syncthreads();
    for (int d = 1; d < 128; d <<= 1) {
        int add = (t >= d && t < 128) ? s[t - d] : 0;
        __syncthreads();
        if (t < 128) s[t] += add;
        __syncthreads();
    }
    if (t < 128) {
        int pos = p0 + s[t] - v;
        int node = n0 + t;
        if (node < N_NODES) rowptr[node] = pos;
        h[t] = pos;
    }
    __syncthreads();
    for (int i = p0 + t; i < p1; i += 256) {
        uint2 pr = pairs[i];
        int pos = atomicAdd(&h[pr.x & 127], 1);
        stgt[pos] = (int)pr.y;
    }
}

// ------- k_agg7: 16 lanes/node, 4 nodes/wave, zero-duplication ------------
// Wave = 4 nodes; lane = (nl = lane>>4, s = lane&15). Lane owns 8 feats
// (seg s) x ALL 8 heads of its node. Chunk = 8 edges per node.
// Per-wave LDS buffer (x2 dbuf, 9216B):
//   [0, 1024):      per node nl*256: atgt staged (e*32 + half*16),
//                   overwritten in-place by fp32 weights w[e][h] (e*32+h*4)
//   [1024, 9216):   X: per node nl*2048 + e*256 + s*16 (bf16 rows)
// Staged by 9 wave-wide global_load_lds (1KB each, all lanes distinct).
// Weight phase: lane=(nl, we=(lane&15)>>1, hq=lane&1) -> 4 exps/chunk.
// Compute: per e (4 edges at once): 3 ds_read_b128 + 8 unpack/splat +
// 32 v_pk_fma_f32 (heads paired in pk halves).
__global__ __launch_bounds__(128) void k_agg7(const int* __restrict__ rowptr,
                                              const int* __restrict__ stgt,
                                              const float* __restrict__ asrc,
                                              const float* __restrict__ atgt,
                                              const unsigned short* __restrict__ xb,
                                              unsigned short* __restrict__ aggout) {
    __shared__ char lds[2 * 2 * 9216];   // 36864 B
    const int tid = threadIdx.x;
    const int wid = tid >> 6, lane = tid & 63;
    const int nl = lane >> 4;            // node-in-wave
    const int s = lane & 15;             // x segment (16B = 8 bf16)
    const int node = blockIdx.x * 8 + wid * 4 + nl;   // grid 12500 exact
    const int base = rowptr[node], end = rowptr[node + 1];
    const int deg = end - base;
    char* wb = lds + wid * 18432;

    const int we = (lane & 15) >> 1;     // weight-phase edge slot
    const int hq = lane & 1;             // head quad
    const float4 asr4 = *reinterpret_cast<const float4*>(asrc + (size_t)node * 8 + hq * 4);
    const int e8 = lane & 7;             // edge-index slot

    float2 acc[8][4] = {};               // [feat f][head-pair hp]
    float4 den4 = {0.f, 0.f, 0.f, 0.f};

    int nch = (deg + 7) >> 3;
    nch = max(nch, __shfl_xor(nch, 16));
    nch = max(nch, __shfl_xor(nch, 32));

    auto eidx = [&](int c) {
        int i = base + c * 8 + e8;
        int hi = end - 1;
        if (i > hi) i = hi;
        if (i < 0) i = 0;
        return i;
    };
    auto stage = [&](char* buf, int t8) {
        // atgt: lane -> (n=lane>>4, e=(lane>>1)&7, half=lane&1); dest = lane*16
        int ta = __shfl(t8, (lane & 0x30) | ((lane >> 1) & 7));
        gll16(atgt + (size_t)ta * 8 + (lane & 1) * 4, buf);
        // X: inst q covers flat i=q*64+lane -> (n=i>>7, e=(i>>4)&7, s=i&15)
#pragma unroll
        for (int q = 0; q < 8; ++q) {
            int te = __shfl(t8, ((q >> 1) << 4) | ((q & 1) << 2) | (lane >> 4));
            gll16(xb + (size_t)te * 128 + s * 8, buf + 1024 + q * 1024);
        }
    };

#define PK(ACC, X2, W2) \
    asm("v_pk_fma_f32 %0, %1, %2, %0" : "+v"(ACC) : "v"(X2), "v"(W2));

    if (nch > 0) {
        int t8 = stgt[eidx(0)];
        stage(wb, t8);
        if (nch > 1) t8 = stgt[eidx(1)];
        asm volatile("s_waitcnt vmcnt(0)" ::: "memory");
        int cur = 0;
        for (int c = 0; c < nch; ++c) {
            if (c + 1 < nch) {
                stage(wb + (cur ^ 1) * 9216, t8);
                if (c + 2 < nch) t8 = stgt[eidx(c + 2)];
            }
            char* buf = wb + cur * 9216;
            // ---- weight phase: lane (nl, we, hq), in-place over [0,1024)
            {
                char* wp = buf + nl * 256 + we * 32 + hq * 16;
                float4 at4 = *reinterpret_cast<const float4*>(wp);
                int cnt = deg - c * 8;           // may be <=0 or >8
                bool ok = (we < cnt);
                float z0 = asr4.x + at4.x, z1 = asr4.y + at4.y;
                float z2 = asr4.z + at4.z, z3 = asr4.w + at4.w;
                float q0 = (z0 > 0.f) ? -z0 : -(ALPHA * z0);
                float q1 = (z1 > 0.f) ? -z1 : -(ALPHA * z1);
                float q2 = (z2 > 0.f) ? -z2 : -(ALPHA * z2);
                float q3 = (z3 > 0.f) ? -z3 : -(ALPHA * z3);
                float4 w4;
                w4.x = ok ? __expf(q0) : 0.f;
                w4.y = ok ? __expf(q1) : 0.f;
                w4.z = ok ? __expf(q2) : 0.f;
                w4.w = ok ? __expf(q3) : 0.f;
                den4.x += w4.x; den4.y += w4.y; den4.z += w4.z; den4.w += w4.w;
                *reinterpret_cast<float4*>(wp) = w4;
            }
            asm volatile("s_waitcnt lgkmcnt(0)" ::: "memory");
            __builtin_amdgcn_sched_barrier(0);
            // ---- compute phase: 8 e-iters, 4 edges (nodes) each
            const char* Xn = buf + 1024 + nl * 2048;
            const char* Wn = buf + nl * 256;
#pragma unroll
            for (int e = 0; e < 8; ++e) {
                uint4 xu = *reinterpret_cast<const uint4*>(Xn + e * 256 + s * 16);
                float4 wa = *reinterpret_cast<const float4*>(Wn + e * 32);
                float4 wbv = *reinterpret_cast<const float4*>(Wn + e * 32 + 16);
                float2 w01 = {wa.x, wa.y}, w23 = {wa.z, wa.w};
                float2 w45 = {wbv.x, wbv.y}, w67 = {wbv.z, wbv.w};
#pragma unroll
                for (int i = 0; i < 4; ++i) {
                    unsigned int u = (&xu.x)[i];
                    float xlo = __builtin_bit_cast(float, u << 16);
                    float xhi = __builtin_bit_cast(float, u & 0xFFFF0000u);
                    float2 xl2 = {xlo, xlo};
                    float2 xh2 = {xhi, xhi};
                    PK(acc[2 * i][0], xl2, w01)
                    PK(acc[2 * i][1], xl2, w23)
                    PK(acc[2 * i][2], xl2, w45)
                    PK(acc[2 * i][3], xl2, w67)
                    PK(acc[2 * i + 1][0], xh2, w01)
                    PK(acc[2 * i + 1][1], xh2, w23)
                    PK(acc[2 * i + 1][2], xh2, w45)
                    PK(acc[2 * i + 1][3], xh2, w67)
                }
            }
            asm volatile("s_waitcnt vmcnt(0)" ::: "memory");
            cur ^= 1;
        }
    }
#undef PK

    // ---- den reduce over the 8 we-slots (lane bits 1..3 within node group)
    for (int d = 2; d <= 8; d <<= 1) {
        den4.x += __shfl_xor(den4.x, d);
        den4.y += __shfl_xor(den4.y, d);
        den4.z += __shfl_xor(den4.z, d);
        den4.w += __shfl_xor(den4.w, d);
    }
    float4 inv4;
    inv4.x = 1.f / (den4.x + 1e-10f);
    inv4.y = 1.f / (den4.y + 1e-10f);
    inv4.z = 1.f / (den4.z + 1e-10f);
    inv4.w = 1.f / (den4.w + 1e-10f);
    // broadcast both head-quads of this lane's node
    int lq0 = lane & 0x30;
    float iv[8];
    iv[0] = __shfl(inv4.x, lq0);     iv[1] = __shfl(inv4.y, lq0);
    iv[2] = __shfl(inv4.z, lq0);     iv[3] = __shfl(inv4.w, lq0);
    iv[4] = __shfl(inv4.x, lq0 | 1); iv[5] = __shfl(inv4.y, lq0 | 1);
    iv[6] = __shfl(inv4.z, lq0 | 1); iv[7] = __shfl(inv4.w, lq0 | 1);

#pragma unroll
    for (int h = 0; h < 8; ++h) {
        ushort8 o;
#pragma unroll
        for (int f = 0; f < 8; ++f) {
            float v = (h & 1) ? acc[f][h >> 1].y : acc[f][h >> 1].x;
            o[f] = f2b(v * iv[h]);
        }
        *reinterpret_cast<ushort8*>(aggout + (size_t)node * 1024 + h * 128 + s * 8) = o;
    }
}

// ------- final per-head GEMM: out[r][h*64+f] = agg[r][h][:] @ W[h][:][f] ---
#define LDK2 136
__global__ __launch_bounds__(256) void k_gemm2(const unsigned short* __restrict__ agg,
                                               const unsigned short* __restrict__ Wt,
                                               float* __restrict__ out) {
    __shared__ unsigned short Al[64 * LDK2];
    __shared__ unsigned short Bl[64 * LDK2];
    const int tid = threadIdx.x;
    const int h = blockIdx.y;
    const int r0 = blockIdx.x * 64;
    for (int it = 0; it < 4; ++it) {
        int idx = tid + it * 256;
        int r = idx >> 4, k8 = (idx & 15) << 3;
        int gr = r0 + r;
        if (gr >= N_NODES) gr = N_NODES - 1;
        *reinterpret_cast<ushort8*>(&Al[r * LDK2 + k8]) =
            *reinterpret_cast<const ushort8*>(agg + (size_t)gr * 1024 + h * 128 + k8);
    }
    for (int it = 0; it < 4; ++it) {
        int idx = tid + it * 256;
        int f = idx >> 4, k8 = (idx & 15) << 3;
        *reinterpret_cast<ushort8*>(&Bl[f * LDK2 + k8]) =
            *reinterpret_cast<const ushort8*>(Wt + (size_t)(h * 64 + f) * 128 + k8);
    }
    __syncthreads();
    const int lane = tid & 63, w = tid >> 6;
    const int l15 = lane & 15, lq = lane >> 4;
    f32x4 acc[4] = {};
    for (int ks = 0; ks < 4; ++ks) {
        int koff = ks * 32 + lq * 8;
        bf16x8 af = *reinterpret_cast<const bf16x8*>(&Al[(w * 16 + l15) * LDK2 + koff]);
#pragma unroll
        for (int n = 0; n < 4; ++n) {
            bf16x8 bf_ = *reinterpret_cast<const bf16x8*>(&Bl[(n * 16 + l15) * LDK2 + koff]);
            acc[n] = __builtin_amdgcn_mfma_f32_16x16x32_bf16(af, bf_, acc[n], 0, 0, 0);
        }
    }
    for (int n = 0; n < 4; ++n) {
        int col = h * 64 + n * 16 + l15;
        int rbase = r0 + w * 16 + lq * 4;
#pragma unroll
        for (int r2 = 0; r2 < 4; ++r2) {
            int rr = rbase + r2;
            if (rr < N_NODES) out[(size_t)rr * 512 + col] = acc[n][r2];
        }
    }
}

extern "C" void kernel_launch(void* const* d_in, const int* in_sizes, int n_in,
                              void* d_out, int out_size, void* d_ws, size_t ws_size,
                              hipStream_t stream) {
    const float* x = (const float*)d_in[0];
    const int* edges = (const int*)d_in[1];
    const float* W = (const float*)d_in[2];
    const float* a = (const float*)d_in[3];
    float* out = (float*)d_out;
    const int* src = edges;
    const int* tgt = edges + N_EDGES;

    char* ws = (char*)d_ws;
    size_t off = 0;
    auto alloc = [&](size_t bytes) -> void* {
        void* p = (void*)(ws + off);
        off += (bytes + 255) & ~(size_t)255;
        return p;
    };
    unsigned short* Wt = (unsigned short*)alloc((size_t)HEADS * OUT_F * IN_F * 2);
    float* u = (float*)alloc(HEADS * IN_F * 4);
    float* v = (float*)alloc(HEADS * IN_F * 4);
    unsigned short* xb = (unsigned short*)alloc((size_t)N_NODES * IN_F * 2);  // 25.6 MB
    float* asrc = (float*)alloc((size_t)N_NODES * 8 * 4);
    float* atgt = (float*)alloc((size_t)N_NODES * 8 * 4);
    int* bhist = (int*)alloc((size_t)NBUCK * 4);
    int* bstart = (int*)alloc((size_t)(NBUCK + 1) * 4);
    int* bcursor = (int*)alloc((size_t)NBUCK * 4);
    int* rowptr = (int*)alloc((size_t)(N_NODES + 1) * 4);
    uint2* pairs = (uint2*)alloc((size_t)N_EDGES * 8);   // 25.6 MB
    int* stgt = (int*)alloc((size_t)N_EDGES * 4);        // 12.8 MB
    (void)ws_size; (void)n_in; (void)in_sizes; (void)out_size;

    hipMemsetAsync(bhist, 0, (size_t)NBUCK * 4, stream);
    k_prep_w<<<256, 256, 0, stream>>>(W, Wt);
    k_uv<<<1, 1024, 0, stream>>>(W, a, u, v);
    k_xadot<<<25000, 256, 0, stream>>>(x, u, v, xb, asrc, atgt);
    k_bcount<<<NPBLK, 256, 0, stream>>>(src, bhist);
    k_bscan<<<1, 1024, 0, stream>>>(bhist, bstart, bcursor, rowptr);
    k_bscatter<<<NPBLK, 256, 0, stream>>>(src, tgt, bcursor, pairs);
    k_bsort<<<NBUCK, 256, 0, stream>>>(pairs, bstart, rowptr, stgt);
    k_agg7<<<12500, 128, 0, stream>>>(rowptr, stgt, asrc, atgt, xb,
                                      (unsigned short*)d_out);
    k_gemm2<<<dim3(1563, 8), 256, 0, stream>>>((const unsigned short*)d_out, Wt, out);
}